// Round 9
// baseline (352.559 us; speedup 1.0000x reference)
//
#include <hip/hip_runtime.h>

// ---------------------------------------------------------------------------
// GCN 3-layer forward on MI355X — fp16 MFMA, fused-pipeline + fused CSR build.
//   L1: hs_u = x@W1 (UNscaled);  agg1 folds dis[src] into the gather.
//   L2/3: hs = (h@W)*dis[row];   agg:  out = relu(dis[n]*(Σ hs[s]+hs[n])+b)
// Launch graph: memset4(bar) -> build(zero+wconv / count / scan, grid-barrier)
//   -> [gemm1 | fill] -> agg1 -> gemm2 -> agg2 -> gemm3 -> agg3   (8 dispatches)
// build uses a software device-scope barrier; 512 blocks x 256 thr, low VGPR,
// 3KB LDS -> 8 blocks/CU capacity >= co-residency requirement.
// ---------------------------------------------------------------------------

typedef _Float16 half8_t __attribute__((ext_vector_type(8)));
typedef float floatx16 __attribute__((ext_vector_type(16)));

#define BUILD_BLOCKS 512

// per-block int64 detection: odd 32-bit words of first 64 entries all zero
__device__ __forceinline__ int detect_is64_block(const void* ei) {
    __shared__ int s_is64;
    if (threadIdx.x == 0) {
        const int* q = (const int*)ei;
        int z = 1;
        for (int k = 1; k < 128; k += 2) {
            if (q[k] != 0) { z = 0; break; }
        }
        s_is64 = z;
    }
    __syncthreads();
    return s_is64;
}

// device-scope grid barrier (monotonic counter; bar must start at 0)
__device__ __forceinline__ void grid_bar(int* bar, int phase, int nblk) {
    __syncthreads();
    if (threadIdx.x == 0) {
        __threadfence();  // release: make prior writes device-visible
        __hip_atomic_fetch_add(bar, 1, __ATOMIC_RELAXED, __HIP_MEMORY_SCOPE_AGENT);
        while (__hip_atomic_load(bar, __ATOMIC_RELAXED, __HIP_MEMORY_SCOPE_AGENT)
               < phase * nblk) {}
        __threadfence();  // acquire
    }
    __syncthreads();
}

// ---- fused build: zero deg + W-conv | count | scan(off/curs/dis) -----------
__global__ __launch_bounds__(256) void build_kernel(
        const void* __restrict__ ei, int* __restrict__ deg, int* __restrict__ off,
        int* __restrict__ curs, float* __restrict__ dis, int N, int E,
        const float* __restrict__ W1, const float* __restrict__ W2,
        const float* __restrict__ W3, _Float16* __restrict__ Wt1,
        _Float16* __restrict__ Wt2, _Float16* __restrict__ Wt3,
        int* __restrict__ bar, int* __restrict__ blockSums) {
    const int tid = threadIdx.x, bid = blockIdx.x;
    const int G = gridDim.x;
    const int gstride = G * 256;
    const int gtid = bid * 256 + tid;

    // phase 0: zero deg + weight transpose/convert
    for (int i = gtid; i < N; i += gstride) deg[i] = 0;
    for (int id = gtid; id < 106496; id += gstride) {
        if (id < 65536) {                       // W1: 256x256 -> Wt1[256][256]
            int n = id >> 8, k = id & 255;
            Wt1[n * 256 + k] = (_Float16)W1[k * 256 + n];
        } else if (id < 98304) {                // W2: 256x128 -> Wt2[128][256]
            int i2 = id - 65536;
            int n = i2 >> 8, k = i2 & 255;
            Wt2[n * 256 + k] = (_Float16)W2[k * 128 + n];
        } else {                                // W3: 128x64 -> Wt3[64][128]
            int i2 = id - 98304;
            int n = i2 >> 7, k = i2 & 127;
            Wt3[n * 128 + k] = (_Float16)W3[k * 64 + n];
        }
    }
    int is64 = detect_is64_block(ei);
    grid_bar(bar, 1, G);

    // phase 1: count degrees, 2 edges/thread
    for (int e0 = gtid * 2; e0 < E; e0 += gstride * 2) {
        if (is64) {
            const long long* dst = (const long long*)ei + E;
            if (e0 + 1 < E) {
                int4 v = *(const int4*)(dst + e0);
                atomicAdd(&deg[v.x], 1);
                atomicAdd(&deg[v.z], 1);
            } else {
                atomicAdd(&deg[(int)dst[e0]], 1);
            }
        } else {
            const int* dst = (const int*)ei + E;
            if (e0 + 1 < E) {
                int2 v = *(const int2*)(dst + e0);
                atomicAdd(&deg[v.x], 1);
                atomicAdd(&deg[v.y], 1);
            } else {
                atomicAdd(&deg[dst[e0]], 1);
            }
        }
    }
    grid_bar(bar, 2, G);

    // phase 2a: per-block inclusive scan of its chunk (chunk <= 256)
    const int chunk = (N + G - 1) / G;   // 40 for N=20000,G=512
    const int base = bid * chunk;
    int v = 0;
    if (tid < chunk && base + tid < N) v = deg[base + tid];
    __shared__ int lsum[256];
    lsum[tid] = v;
    __syncthreads();
    #pragma unroll
    for (int d = 1; d < 256; d <<= 1) {
        int t2 = (tid >= d) ? lsum[tid - d] : 0;
        __syncthreads();
        lsum[tid] += t2;
        __syncthreads();
    }
    if (tid == 0) blockSums[bid] = lsum[255];
    grid_bar(bar, 3, G);

    // phase 2b: block 0 scans the 512 block sums (inclusive, in place)
    if (bid == 0) {
        __shared__ int bs[BUILD_BLOCKS];
        bs[tid] = blockSums[tid];
        bs[tid + 256] = blockSums[tid + 256];
        __syncthreads();
        for (int d = 1; d < BUILD_BLOCKS; d <<= 1) {
            int a = (tid >= d) ? bs[tid - d] : 0;
            int b = (tid + 256 >= d) ? bs[tid + 256 - d] : 0;
            __syncthreads();
            bs[tid] += a;
            bs[tid + 256] += b;
            __syncthreads();
        }
        blockSums[tid] = bs[tid];
        blockSums[tid + 256] = bs[tid + 256];
    }
    grid_bar(bar, 4, G);

    // phase 2c: write off/curs/dis
    int prefix = (bid > 0) ? blockSums[bid - 1] : 0;
    if (tid < chunk && base + tid < N) {
        int o = prefix + lsum[tid] - v;   // exclusive
        off[base + tid] = o;
        curs[base + tid] = o;
        dis[base + tid] = rsqrtf((float)(v + 1));
    }
    if (bid == G - 1 && tid == 0) off[N] = E;
}

// ---- fill CSR: 2 edges/thread (runs fused with gemm1) ----------------------
__device__ void fill_body(int blk, const void* ei, int* __restrict__ cur,
                          int* __restrict__ csr, int E) {
    int is64 = detect_is64_block(ei);
    int e0 = (blk * 256 + threadIdx.x) * 2;
    int s0 = 0, s1 = 0, d0 = 0, d1 = 0, n = 0;
    if (is64) {
        const long long* src = (const long long*)ei;
        const long long* dst = src + E;
        if (e0 + 1 < E) {
            int4 vs = *(const int4*)(src + e0);
            int4 vd = *(const int4*)(dst + e0);
            s0 = vs.x; s1 = vs.z; d0 = vd.x; d1 = vd.z; n = 2;
        } else if (e0 < E) { s0 = (int)src[e0]; d0 = (int)dst[e0]; n = 1; }
    } else {
        const int* src = (const int*)ei;
        const int* dst = src + E;
        if (e0 + 1 < E) {
            int2 vs = *(const int2*)(src + e0);
            int2 vd = *(const int2*)(dst + e0);
            s0 = vs.x; s1 = vs.y; d0 = vd.x; d1 = vd.y; n = 2;
        } else if (e0 < E) { s0 = src[e0]; d0 = dst[e0]; n = 1; }
    }
    if (n >= 1) { int slot = atomicAdd(&cur[d0], 1); csr[slot] = s0; }
    if (n == 2) { int slot = atomicAdd(&cur[d1], 1); csr[slot] = s1; }
}

// ---- MFMA GEMM body: C = (A @ Wt^T) [* dis[row] if SCALE], fp16 out --------
template <typename AT, bool SCALE>
__device__ void gemm_body(int bx, int by, const AT* __restrict__ A,
                          const _Float16* __restrict__ Wt, const float* __restrict__ dis,
                          _Float16* __restrict__ C, int M, int N, int K) {
    constexpr int BM = 128, BN = 64, BK = 32, PAD = 8;
    __shared__ _Float16 As[BM][BK + PAD];
    __shared__ _Float16 Bs[BN][BK + PAD];
    __shared__ float disS[BM];
    const int tid = threadIdx.x;
    const int wave = tid >> 6, lane = tid & 63;
    const int row0 = bx * BM, col0 = by * BN;

    if constexpr (SCALE) {
        if (tid < BM) { int r = row0 + tid; disS[tid] = (r < M) ? dis[r] : 0.f; }
    }

    const int ar0 = tid >> 2, ar1 = ar0 + 64;
    const int ac  = (tid & 3) * 8;
    const int br  = tid >> 2;
    const int bc  = (tid & 3) * 8;
    const long long arow0 = (long long)(row0 + ar0) * K;
    const long long arow1 = (long long)(row0 + ar1) * K;
    const long long brow  = (long long)(col0 + br) * K;
    const bool a0ok = (row0 + ar0) < M, a1ok = (row0 + ar1) < M;
    const float4 f4z = make_float4(0.f, 0.f, 0.f, 0.f);

    float4 pa0lo = f4z, pa0hi = f4z, pa1lo = f4z, pa1hi = f4z, pb;

    auto loadA = [&](int k0) {
        if constexpr (sizeof(AT) == 2) {
            if (a0ok) pa0lo = *(const float4*)((const _Float16*)A + arow0 + k0 + ac);
            if (a1ok) pa1lo = *(const float4*)((const _Float16*)A + arow1 + k0 + ac);
        } else {
            const float* p0 = (const float*)A + arow0 + k0 + ac;
            const float* p1 = (const float*)A + arow1 + k0 + ac;
            if (a0ok) { pa0lo = *(const float4*)p0; pa0hi = *(const float4*)(p0 + 4); }
            if (a1ok) { pa1lo = *(const float4*)p1; pa1hi = *(const float4*)(p1 + 4); }
        }
        pb = *(const float4*)(Wt + brow + k0 + bc);
    };
    auto storeA = [&]() {
        if constexpr (sizeof(AT) == 2) {
            *(float4*)&As[ar0][ac] = pa0lo;
            *(float4*)&As[ar1][ac] = pa1lo;
        } else {
            half8_t h0, h1;
            h0[0] = (_Float16)pa0lo.x; h0[1] = (_Float16)pa0lo.y;
            h0[2] = (_Float16)pa0lo.z; h0[3] = (_Float16)pa0lo.w;
            h0[4] = (_Float16)pa0hi.x; h0[5] = (_Float16)pa0hi.y;
            h0[6] = (_Float16)pa0hi.z; h0[7] = (_Float16)pa0hi.w;
            h1[0] = (_Float16)pa1lo.x; h1[1] = (_Float16)pa1lo.y;
            h1[2] = (_Float16)pa1lo.z; h1[3] = (_Float16)pa1lo.w;
            h1[4] = (_Float16)pa1hi.x; h1[5] = (_Float16)pa1hi.y;
            h1[6] = (_Float16)pa1hi.z; h1[7] = (_Float16)pa1hi.w;
            *(half8_t*)&As[ar0][ac] = h0;
            *(half8_t*)&As[ar1][ac] = h1;
        }
        *(float4*)&Bs[br][bc] = pb;
    };

    loadA(0);
    storeA();
    __syncthreads();

    floatx16 acc0, acc1;
    #pragma unroll
    for (int i = 0; i < 16; ++i) { acc0[i] = 0.f; acc1[i] = 0.f; }

    const _Float16* ap  = &As[wave * 32 + (lane & 31)][(lane >> 5) * 8];
    const _Float16* bp0 = &Bs[lane & 31][(lane >> 5) * 8];
    const _Float16* bp1 = &Bs[32 + (lane & 31)][(lane >> 5) * 8];

    const int niter = K / BK;
    for (int it = 0; it < niter; ++it) {
        const bool more = (it + 1) < niter;
        if (more) loadA((it + 1) * BK);
        half8_t a0  = *(const half8_t*)ap;
        half8_t a1  = *(const half8_t*)(ap + 16);
        half8_t b00 = *(const half8_t*)bp0;
        half8_t b01 = *(const half8_t*)(bp0 + 16);
        half8_t b10 = *(const half8_t*)bp1;
        half8_t b11 = *(const half8_t*)(bp1 + 16);
        acc0 = __builtin_amdgcn_mfma_f32_32x32x16_f16(a0, b00, acc0, 0, 0, 0);
        acc1 = __builtin_amdgcn_mfma_f32_32x32x16_f16(a0, b10, acc1, 0, 0, 0);
        acc0 = __builtin_amdgcn_mfma_f32_32x32x16_f16(a1, b01, acc0, 0, 0, 0);
        acc1 = __builtin_amdgcn_mfma_f32_32x32x16_f16(a1, b11, acc1, 0, 0, 0);
        if (more) {
            __syncthreads();
            storeA();
            __syncthreads();
        }
    }

    const int colb = lane & 31, q = lane >> 5;
    #pragma unroll
    for (int r = 0; r < 16; ++r) {
        int rl = wave * 32 + (r & 3) + 8 * (r >> 2) + 4 * q;
        int row = row0 + rl;
        if (row >= M) continue;
        float d = SCALE ? disS[rl] : 1.0f;
        C[(long long)row * N + col0 + colb]      = (_Float16)(acc0[r] * d);
        C[(long long)row * N + col0 + 32 + colb] = (_Float16)(acc1[r] * d);
    }
}

// ---- fused launches --------------------------------------------------------
__global__ __launch_bounds__(256) void fused_gemm1_fill_kernel(
        const float* x, const _Float16* Wt1, _Float16* C, int M, int gM, int nGemm,
        const void* ei, int* cur, int* csr, int E) {
    if ((int)blockIdx.x < nGemm) {
        gemm_body<float, false>(blockIdx.x % gM, blockIdx.x / gM, x, Wt1, nullptr,
                                C, M, 256, 256);
    } else {
        fill_body(blockIdx.x - nGemm, ei, cur, csr, E);
    }
}

__global__ __launch_bounds__(256) void gemm_kernel(
        const _Float16* A, const _Float16* Wt, const float* dis, _Float16* C,
        int M, int N, int K) {
    gemm_body<_Float16, true>(blockIdx.x, blockIdx.y, A, Wt, dis, C, M, N, K);
}

// ---- aggregation: wave/node, 16B lanes, multi-edge wave-loads --------------
__device__ __forceinline__ void vload8h(float* d, const _Float16* p) {
    half8_t v = *(const half8_t*)p;
    #pragma unroll
    for (int i = 0; i < 8; ++i) d[i] = (float)v[i];
}

template <int F, bool OUT_HALF, int U, bool SCALE_SRC>
__global__ __launch_bounds__(256) void agg_kernel(
        const _Float16* __restrict__ hs, const float* __restrict__ dis,
        const float* __restrict__ bias, const int* __restrict__ off,
        const int* __restrict__ csr, void* __restrict__ outv,
        int N, int do_relu) {
    constexpr int LPE = F / 8;     // lanes per edge-row (16B each)
    constexpr int EPL = 64 / LPE;  // edge rows per wave-load
    constexpr int STEP = U * EPL;  // edges per main-loop iter
    const int wave = threadIdx.x >> 6;
    const int lane = threadIdx.x & 63;
    const int n = blockIdx.x * 4 + wave;
    if (n >= N) return;
    const int fl = lane % LPE;     // feature slice
    const int es = lane / LPE;     // edge slot
    const int fo = fl * 8;
    const float dn = dis[n];

    float acc[8];
    if (es == 0) {
        vload8h(acc, hs + (long long)n * F + fo);  // self-loop term
        if constexpr (SCALE_SRC) {
            #pragma unroll
            for (int k = 0; k < 8; ++k) acc[k] *= dn;
        }
    } else {
        #pragma unroll
        for (int v = 0; v < 8; ++v) acc[v] = 0.f;
    }

    const int s0 = off[n], s1 = off[n + 1];
    int j = s0;
    for (; j + STEP <= s1; j += STEP) {
        int idx[U];
        #pragma unroll
        for (int u = 0; u < U; ++u) idx[u] = csr[j + u * EPL + es];
        float ds[U];
        if constexpr (SCALE_SRC) {
            #pragma unroll
            for (int u = 0; u < U; ++u) ds[u] = dis[idx[u]];
        }
        float v[U][8];
        #pragma unroll
        for (int u = 0; u < U; ++u)
            vload8h(v[u], hs + (long long)idx[u] * F + fo);
        #pragma unroll
        for (int u = 0; u < U; ++u) {
            #pragma unroll
            for (int k = 0; k < 8; ++k)
                acc[k] += SCALE_SRC ? v[u][k] * ds[u] : v[u][k];
        }
    }
    if (j < s1) {  // masked tail
        #pragma unroll
        for (int u = 0; u < U; ++u) {
            int e = j + u * EPL + es;
            if (e < s1) {
                int ii = csr[e];
                float sc = SCALE_SRC ? dis[ii] : 1.0f;
                float v[8];
                vload8h(v, hs + (long long)ii * F + fo);
                #pragma unroll
                for (int k = 0; k < 8; ++k) acc[k] += v[k] * sc;
            }
        }
    }

    // fold edge-slot partials down to lanes < LPE
    #pragma unroll
    for (int offd = 32; offd >= LPE; offd >>= 1) {
        #pragma unroll
        for (int k = 0; k < 8; ++k) acc[k] += __shfl_down(acc[k], offd);
    }

    if (lane < LPE) {
        float4 b0 = *(const float4*)(bias + fo);
        float4 b1 = *(const float4*)(bias + fo + 4);
        float bb[8] = {b0.x, b0.y, b0.z, b0.w, b1.x, b1.y, b1.z, b1.w};
        float o[8];
        #pragma unroll
        for (int k = 0; k < 8; ++k) {
            float val = dn * acc[k] + bb[k];
            o[k] = do_relu ? fmaxf(val, 0.f) : val;
        }
        if constexpr (OUT_HALF) {
            half8_t h;
            #pragma unroll
            for (int k = 0; k < 8; ++k) h[k] = (_Float16)o[k];
            *(half8_t*)((_Float16*)outv + (long long)n * F + fo) = h;
        } else {
            float* op = (float*)outv + (long long)n * F + fo;
            *(float4*)op       = make_float4(o[0], o[1], o[2], o[3]);
            *(float4*)(op + 4) = make_float4(o[4], o[5], o[6], o[7]);
        }
    }
}

// ---------------------------------------------------------------------------
extern "C" void kernel_launch(void* const* d_in, const int* in_sizes, int n_in,
                              void* d_out, int out_size, void* d_ws, size_t ws_size,
                              hipStream_t stream) {
    const float* x  = (const float*)d_in[0];
    const float* W1 = (const float*)d_in[1];
    const float* b1 = (const float*)d_in[2];
    const float* W2 = (const float*)d_in[3];
    const float* b2 = (const float*)d_in[4];
    const float* W3 = (const float*)d_in[5];
    const float* b3 = (const float*)d_in[6];
    const void*  ei = d_in[7];

    const int N = in_sizes[0] / 256;      // 20000
    const int E = in_sizes[7] / 2;        // 320000

    size_t cur = 0;
    auto alloc = [&](size_t bytes) -> void* {
        void* p = (char*)d_ws + cur;
        cur += (bytes + 255) & ~(size_t)255;
        return p;
    };
    int*      bar  = (int*)alloc(4);
    int*      bsum = (int*)alloc(BUILD_BLOCKS * 4);
    int*      deg  = (int*)alloc((size_t)N * 4);
    float*    dis  = (float*)alloc((size_t)N * 4);
    int*      off  = (int*)alloc((size_t)(N + 1) * 4);
    int*      curs = (int*)alloc((size_t)N * 4);
    int*      csr  = (int*)alloc((size_t)E * 4);
    _Float16* Wt1  = (_Float16*)alloc(256 * 256 * 2);
    _Float16* Wt2  = (_Float16*)alloc(128 * 256 * 2);
    _Float16* Wt3  = (_Float16*)alloc(64 * 128 * 2);
    _Float16* bufC = (_Float16*)alloc((size_t)N * 256 * 2);
    _Float16* bufH = (_Float16*)alloc((size_t)N * 256 * 2);
    (void)ws_size; (void)n_in; (void)out_size;

    const int gM   = (N + 127) / 128;            // 157
    const int nCnt = (E / 2 + 255) / 256;        // 625 (2 edges/thread)
    const int nGm1 = gM * 4;                     // 628
    const int gAgg = (N + 3) / 4;

    hipMemsetAsync(bar, 0, 4, stream);
    build_kernel<<<BUILD_BLOCKS, 256, 0, stream>>>(
        ei, deg, off, curs, dis, N, E, W1, W2, W3, Wt1, Wt2, Wt3, bar, bsum);
    fused_gemm1_fill_kernel<<<nGm1 + nCnt, 256, 0, stream>>>(
        x, Wt1, bufC, N, gM, nGm1, ei, curs, csr, E);

    agg_kernel<256, true, 4, true><<<gAgg, 256, 0, stream>>>(
        bufC, dis, b1, off, csr, bufH, N, 1);
    gemm_kernel<<<dim3(gM, 2), 256, 0, stream>>>(bufH, Wt2, dis, bufC, N, 128, 256);
    agg_kernel<128, true, 4, false><<<gAgg, 256, 0, stream>>>(
        bufC, dis, b2, off, csr, bufH, N, 1);
    gemm_kernel<<<dim3(gM, 1), 256, 0, stream>>>(bufH, Wt3, dis, bufC, N, 64, 128);
    agg_kernel<64, false, 2, false><<<gAgg, 256, 0, stream>>>(
        bufC, dis, b3, off, csr, d_out, N, 0);
}

// Round 10
// 217.904 us; speedup vs baseline: 1.6180x; 1.6180x over previous
//
#include <hip/hip_runtime.h>

// ---------------------------------------------------------------------------
// GCN 3-layer forward on MI355X — fp16 MFMA, fused-pipeline edition (R8 cfg).
//   L1: hs_u = x@W1 (UNscaled);  agg1: out = relu(dis[n]*(Σ dis[s]*hs_u[s]
//        + dis[n]*hs_u[n]) + b)          (dis[src] folded into the gather)
//   L2/3: hs = (h@W)*dis[row];   agg:  out = relu(dis[n]*(Σ hs[s]+hs[n])+b)
// Launch graph (all serial on stream):
//   memset(deg) -> [count_deg | W-conv] -> scan -> [gemm1 | fill] ->
//   agg1 -> gemm2 -> agg2 -> gemm3 -> agg3         (9 dispatches)
// NOTE (R9 post-mortem): software grid barriers (512-block spin on a
// device-scope atomic) cost ~40 us/barrier here — kernel boundaries are
// cheaper (~2-4 us). Do not re-fuse the CSR build that way.
// ---------------------------------------------------------------------------

typedef _Float16 half8_t __attribute__((ext_vector_type(8)));
typedef float floatx16 __attribute__((ext_vector_type(16)));

// per-block int64 detection: odd 32-bit words of first 64 entries all zero
__device__ __forceinline__ int detect_is64_block(const void* ei) {
    __shared__ int s_is64;
    if (threadIdx.x == 0) {
        const int* q = (const int*)ei;
        int z = 1;
        for (int k = 1; k < 128; k += 2) {
            if (q[k] != 0) { z = 0; break; }
        }
        s_is64 = z;
    }
    __syncthreads();
    return s_is64;
}

// ---- count: 2 edges/thread -------------------------------------------------
__device__ void count_body(int blk, const void* ei, int* __restrict__ deg, int E) {
    int is64 = detect_is64_block(ei);
    int e0 = (blk * 256 + threadIdx.x) * 2;
    if (is64) {
        const long long* dst = (const long long*)ei + E;
        if (e0 + 1 < E) {
            int4 v = *(const int4*)(dst + e0);   // two little-endian int64
            atomicAdd(&deg[v.x], 1);
            atomicAdd(&deg[v.z], 1);
        } else if (e0 < E) {
            atomicAdd(&deg[(int)dst[e0]], 1);
        }
    } else {
        const int* dst = (const int*)ei + E;
        if (e0 + 1 < E) {
            int2 v = *(const int2*)(dst + e0);
            atomicAdd(&deg[v.x], 1);
            atomicAdd(&deg[v.y], 1);
        } else if (e0 < E) {
            atomicAdd(&deg[dst[e0]], 1);
        }
    }
}

// ---- W[K][N] fp32 -> Wt[N][K] fp16 ----------------------------------------
__device__ void wconv_body(int blk, const float* __restrict__ W1,
                           const float* __restrict__ W2, const float* __restrict__ W3,
                           _Float16* __restrict__ Wt1, _Float16* __restrict__ Wt2,
                           _Float16* __restrict__ Wt3) {
    int id = blk * 256 + threadIdx.x;
    if (id < 65536) {                       // W1: 256x256 -> Wt1[256][256]
        int n = id >> 8, k = id & 255;
        Wt1[n * 256 + k] = (_Float16)W1[k * 256 + n];
    } else if (id < 98304) {                // W2: 256x128 -> Wt2[128][256]
        int i = id - 65536;
        int n = i >> 8, k = i & 255;
        Wt2[n * 256 + k] = (_Float16)W2[k * 128 + n];
    } else if (id < 106496) {               // W3: 128x64 -> Wt3[64][128]
        int i = id - 98304;
        int n = i >> 7, k = i & 127;
        Wt3[n * 128 + k] = (_Float16)W3[k * 64 + n];
    }
}

// ---- fill CSR: 2 edges/thread ---------------------------------------------
__device__ void fill_body(int blk, const void* ei, int* __restrict__ cur,
                          int* __restrict__ csr, int E) {
    int is64 = detect_is64_block(ei);
    int e0 = (blk * 256 + threadIdx.x) * 2;
    int s0 = 0, s1 = 0, d0 = 0, d1 = 0, n = 0;
    if (is64) {
        const long long* src = (const long long*)ei;
        const long long* dst = src + E;
        if (e0 + 1 < E) {
            int4 vs = *(const int4*)(src + e0);
            int4 vd = *(const int4*)(dst + e0);
            s0 = vs.x; s1 = vs.z; d0 = vd.x; d1 = vd.z; n = 2;
        } else if (e0 < E) { s0 = (int)src[e0]; d0 = (int)dst[e0]; n = 1; }
    } else {
        const int* src = (const int*)ei;
        const int* dst = src + E;
        if (e0 + 1 < E) {
            int2 vs = *(const int2*)(src + e0);
            int2 vd = *(const int2*)(dst + e0);
            s0 = vs.x; s1 = vs.y; d0 = vd.x; d1 = vd.y; n = 2;
        } else if (e0 < E) { s0 = src[e0]; d0 = dst[e0]; n = 1; }
    }
    if (n >= 1) { int slot = atomicAdd(&cur[d0], 1); csr[slot] = s0; }
    if (n == 2) { int slot = atomicAdd(&cur[d1], 1); csr[slot] = s1; }
}

// ---- single-block scan: off/curs = exscan(deg), dis = rsqrt(deg+1) ---------
#define SCAN_THREADS 1024
#define SCAN_CHUNK 20
__global__ __launch_bounds__(SCAN_THREADS) void scan_kernel(
        const int* __restrict__ deg, int* __restrict__ off, int* __restrict__ curs,
        float* __restrict__ dis, int N, int E) {
    __shared__ int sums[SCAN_THREADS];
    int t = threadIdx.x;
    int base = t * SCAN_CHUNK;
    int local[SCAN_CHUNK];
    if (base + SCAN_CHUNK <= N) {
        const int4* p = (const int4*)(deg + base);
        #pragma unroll
        for (int i = 0; i < SCAN_CHUNK / 4; ++i) {
            int4 v = p[i];
            local[4 * i] = v.x; local[4 * i + 1] = v.y;
            local[4 * i + 2] = v.z; local[4 * i + 3] = v.w;
        }
    } else {
        for (int i = 0; i < SCAN_CHUNK; ++i) {
            int idx = base + i;
            local[i] = (idx < N) ? deg[idx] : 0;
        }
    }
    int pre[SCAN_CHUNK];
    int s = 0;
    #pragma unroll
    for (int i = 0; i < SCAN_CHUNK; ++i) { pre[i] = s; s += local[i]; }
    sums[t] = s;
    __syncthreads();
    for (int d = 1; d < SCAN_THREADS; d <<= 1) {
        int v = (t >= d) ? sums[t - d] : 0;
        __syncthreads();
        sums[t] += v;
        __syncthreads();
    }
    int prefix = (t > 0) ? sums[t - 1] : 0;
    for (int i = 0; i < SCAN_CHUNK; ++i) {
        int idx = base + i;
        if (idx < N) {
            int o = prefix + pre[i];
            off[idx] = o; curs[idx] = o;
            dis[idx] = rsqrtf((float)(local[i] + 1));
        }
    }
    if (t == 0) off[N] = E;
}

// ---- MFMA GEMM body: C = (A @ Wt^T) [* dis[row] if SCALE], fp16 out --------
template <typename AT, bool SCALE>
__device__ void gemm_body(int bx, int by, const AT* __restrict__ A,
                          const _Float16* __restrict__ Wt, const float* __restrict__ dis,
                          _Float16* __restrict__ C, int M, int N, int K) {
    constexpr int BM = 128, BN = 64, BK = 32, PAD = 8;
    __shared__ _Float16 As[BM][BK + PAD];
    __shared__ _Float16 Bs[BN][BK + PAD];
    __shared__ float disS[BM];
    const int tid = threadIdx.x;
    const int wave = tid >> 6, lane = tid & 63;
    const int row0 = bx * BM, col0 = by * BN;

    if constexpr (SCALE) {
        if (tid < BM) { int r = row0 + tid; disS[tid] = (r < M) ? dis[r] : 0.f; }
    }

    const int ar0 = tid >> 2, ar1 = ar0 + 64;
    const int ac  = (tid & 3) * 8;
    const int br  = tid >> 2;
    const int bc  = (tid & 3) * 8;
    const long long arow0 = (long long)(row0 + ar0) * K;
    const long long arow1 = (long long)(row0 + ar1) * K;
    const long long brow  = (long long)(col0 + br) * K;
    const bool a0ok = (row0 + ar0) < M, a1ok = (row0 + ar1) < M;
    const float4 f4z = make_float4(0.f, 0.f, 0.f, 0.f);

    float4 pa0lo = f4z, pa0hi = f4z, pa1lo = f4z, pa1hi = f4z, pb;

    auto loadA = [&](int k0) {
        if constexpr (sizeof(AT) == 2) {
            if (a0ok) pa0lo = *(const float4*)((const _Float16*)A + arow0 + k0 + ac);
            if (a1ok) pa1lo = *(const float4*)((const _Float16*)A + arow1 + k0 + ac);
        } else {
            const float* p0 = (const float*)A + arow0 + k0 + ac;
            const float* p1 = (const float*)A + arow1 + k0 + ac;
            if (a0ok) { pa0lo = *(const float4*)p0; pa0hi = *(const float4*)(p0 + 4); }
            if (a1ok) { pa1lo = *(const float4*)p1; pa1hi = *(const float4*)(p1 + 4); }
        }
        pb = *(const float4*)(Wt + brow + k0 + bc);
    };
    auto storeA = [&]() {
        if constexpr (sizeof(AT) == 2) {
            *(float4*)&As[ar0][ac] = pa0lo;
            *(float4*)&As[ar1][ac] = pa1lo;
        } else {
            half8_t h0, h1;
            h0[0] = (_Float16)pa0lo.x; h0[1] = (_Float16)pa0lo.y;
            h0[2] = (_Float16)pa0lo.z; h0[3] = (_Float16)pa0lo.w;
            h0[4] = (_Float16)pa0hi.x; h0[5] = (_Float16)pa0hi.y;
            h0[6] = (_Float16)pa0hi.z; h0[7] = (_Float16)pa0hi.w;
            h1[0] = (_Float16)pa1lo.x; h1[1] = (_Float16)pa1lo.y;
            h1[2] = (_Float16)pa1lo.z; h1[3] = (_Float16)pa1lo.w;
            h1[4] = (_Float16)pa1hi.x; h1[5] = (_Float16)pa1hi.y;
            h1[6] = (_Float16)pa1hi.z; h1[7] = (_Float16)pa1hi.w;
            *(half8_t*)&As[ar0][ac] = h0;
            *(half8_t*)&As[ar1][ac] = h1;
        }
        *(float4*)&Bs[br][bc] = pb;
    };

    loadA(0);
    storeA();
    __syncthreads();

    floatx16 acc0, acc1;
    #pragma unroll
    for (int i = 0; i < 16; ++i) { acc0[i] = 0.f; acc1[i] = 0.f; }

    const _Float16* ap  = &As[wave * 32 + (lane & 31)][(lane >> 5) * 8];
    const _Float16* bp0 = &Bs[lane & 31][(lane >> 5) * 8];
    const _Float16* bp1 = &Bs[32 + (lane & 31)][(lane >> 5) * 8];

    const int niter = K / BK;
    for (int it = 0; it < niter; ++it) {
        const bool more = (it + 1) < niter;
        if (more) loadA((it + 1) * BK);
        half8_t a0  = *(const half8_t*)ap;
        half8_t a1  = *(const half8_t*)(ap + 16);
        half8_t b00 = *(const half8_t*)bp0;
        half8_t b01 = *(const half8_t*)(bp0 + 16);
        half8_t b10 = *(const half8_t*)bp1;
        half8_t b11 = *(const half8_t*)(bp1 + 16);
        acc0 = __builtin_amdgcn_mfma_f32_32x32x16_f16(a0, b00, acc0, 0, 0, 0);
        acc1 = __builtin_amdgcn_mfma_f32_32x32x16_f16(a0, b10, acc1, 0, 0, 0);
        acc0 = __builtin_amdgcn_mfma_f32_32x32x16_f16(a1, b01, acc0, 0, 0, 0);
        acc1 = __builtin_amdgcn_mfma_f32_32x32x16_f16(a1, b11, acc1, 0, 0, 0);
        if (more) {
            __syncthreads();
            storeA();
            __syncthreads();
        }
    }

    const int colb = lane & 31, q = lane >> 5;
    #pragma unroll
    for (int r = 0; r < 16; ++r) {
        int rl = wave * 32 + (r & 3) + 8 * (r >> 2) + 4 * q;
        int row = row0 + rl;
        if (row >= M) continue;
        float d = SCALE ? disS[rl] : 1.0f;
        C[(long long)row * N + col0 + colb]      = (_Float16)(acc0[r] * d);
        C[(long long)row * N + col0 + 32 + colb] = (_Float16)(acc1[r] * d);
    }
}

// ---- fused launches --------------------------------------------------------
__global__ __launch_bounds__(256) void fused_count_wconv_kernel(
        const void* ei, int* deg, int E, int nCount,
        const float* W1, const float* W2, const float* W3,
        _Float16* Wt1, _Float16* Wt2, _Float16* Wt3) {
    if ((int)blockIdx.x < nCount) count_body(blockIdx.x, ei, deg, E);
    else wconv_body(blockIdx.x - nCount, W1, W2, W3, Wt1, Wt2, Wt3);
}

__global__ __launch_bounds__(256) void fused_gemm1_fill_kernel(
        const float* x, const _Float16* Wt1, _Float16* C, int M, int gM, int nGemm,
        const void* ei, int* cur, int* csr, int E) {
    if ((int)blockIdx.x < nGemm) {
        gemm_body<float, false>(blockIdx.x % gM, blockIdx.x / gM, x, Wt1, nullptr,
                                C, M, 256, 256);
    } else {
        fill_body(blockIdx.x - nGemm, ei, cur, csr, E);
    }
}

__global__ __launch_bounds__(256) void gemm_kernel(
        const _Float16* A, const _Float16* Wt, const float* dis, _Float16* C,
        int M, int N, int K) {
    gemm_body<_Float16, true>(blockIdx.x, blockIdx.y, A, Wt, dis, C, M, N, K);
}

// ---- aggregation: wave/node, 16B lanes, multi-edge wave-loads --------------
__device__ __forceinline__ void vload8h(float* d, const _Float16* p) {
    half8_t v = *(const half8_t*)p;
    #pragma unroll
    for (int i = 0; i < 8; ++i) d[i] = (float)v[i];
}

template <int F, bool OUT_HALF, int U, bool SCALE_SRC>
__global__ __launch_bounds__(256) void agg_kernel(
        const _Float16* __restrict__ hs, const float* __restrict__ dis,
        const float* __restrict__ bias, const int* __restrict__ off,
        const int* __restrict__ csr, void* __restrict__ outv,
        int N, int do_relu) {
    constexpr int LPE = F / 8;     // lanes per edge-row (16B each)
    constexpr int EPL = 64 / LPE;  // edge rows per wave-load
    constexpr int STEP = U * EPL;  // edges per main-loop iter
    const int wave = threadIdx.x >> 6;
    const int lane = threadIdx.x & 63;
    const int n = blockIdx.x * 4 + wave;
    if (n >= N) return;
    const int fl = lane % LPE;     // feature slice
    const int es = lane / LPE;     // edge slot
    const int fo = fl * 8;
    const float dn = dis[n];

    float acc[8];
    if (es == 0) {
        vload8h(acc, hs + (long long)n * F + fo);  // self-loop term
        if constexpr (SCALE_SRC) {
            #pragma unroll
            for (int k = 0; k < 8; ++k) acc[k] *= dn;
        }
    } else {
        #pragma unroll
        for (int v = 0; v < 8; ++v) acc[v] = 0.f;
    }

    const int s0 = off[n], s1 = off[n + 1];
    int j = s0;
    for (; j + STEP <= s1; j += STEP) {
        int idx[U];
        #pragma unroll
        for (int u = 0; u < U; ++u) idx[u] = csr[j + u * EPL + es];
        float ds[U];
        if constexpr (SCALE_SRC) {
            #pragma unroll
            for (int u = 0; u < U; ++u) ds[u] = dis[idx[u]];
        }
        float v[U][8];
        #pragma unroll
        for (int u = 0; u < U; ++u)
            vload8h(v[u], hs + (long long)idx[u] * F + fo);
        #pragma unroll
        for (int u = 0; u < U; ++u) {
            #pragma unroll
            for (int k = 0; k < 8; ++k)
                acc[k] += SCALE_SRC ? v[u][k] * ds[u] : v[u][k];
        }
    }
    if (j < s1) {  // masked tail
        #pragma unroll
        for (int u = 0; u < U; ++u) {
            int e = j + u * EPL + es;
            if (e < s1) {
                int ii = csr[e];
                float sc = SCALE_SRC ? dis[ii] : 1.0f;
                float v[8];
                vload8h(v, hs + (long long)ii * F + fo);
                #pragma unroll
                for (int k = 0; k < 8; ++k) acc[k] += v[k] * sc;
            }
        }
    }

    // fold edge-slot partials down to lanes < LPE
    #pragma unroll
    for (int offd = 32; offd >= LPE; offd >>= 1) {
        #pragma unroll
        for (int k = 0; k < 8; ++k) acc[k] += __shfl_down(acc[k], offd);
    }

    if (lane < LPE) {
        float4 b0 = *(const float4*)(bias + fo);
        float4 b1 = *(const float4*)(bias + fo + 4);
        float bb[8] = {b0.x, b0.y, b0.z, b0.w, b1.x, b1.y, b1.z, b1.w};
        float o[8];
        #pragma unroll
        for (int k = 0; k < 8; ++k) {
            float val = dn * acc[k] + bb[k];
            o[k] = do_relu ? fmaxf(val, 0.f) : val;
        }
        if constexpr (OUT_HALF) {
            half8_t h;
            #pragma unroll
            for (int k = 0; k < 8; ++k) h[k] = (_Float16)o[k];
            *(half8_t*)((_Float16*)outv + (long long)n * F + fo) = h;
        } else {
            float* op = (float*)outv + (long long)n * F + fo;
            *(float4*)op       = make_float4(o[0], o[1], o[2], o[3]);
            *(float4*)(op + 4) = make_float4(o[4], o[5], o[6], o[7]);
        }
    }
}

// ---------------------------------------------------------------------------
extern "C" void kernel_launch(void* const* d_in, const int* in_sizes, int n_in,
                              void* d_out, int out_size, void* d_ws, size_t ws_size,
                              hipStream_t stream) {
    const float* x  = (const float*)d_in[0];
    const float* W1 = (const float*)d_in[1];
    const float* b1 = (const float*)d_in[2];
    const float* W2 = (const float*)d_in[3];
    const float* b2 = (const float*)d_in[4];
    const float* W3 = (const float*)d_in[5];
    const float* b3 = (const float*)d_in[6];
    const void*  ei = d_in[7];

    const int N = in_sizes[0] / 256;      // 20000
    const int E = in_sizes[7] / 2;        // 320000

    size_t cur = 0;
    auto alloc = [&](size_t bytes) -> void* {
        void* p = (char*)d_ws + cur;
        cur += (bytes + 255) & ~(size_t)255;
        return p;
    };
    int*      deg  = (int*)alloc((size_t)N * 4);
    float*    dis  = (float*)alloc((size_t)N * 4);
    int*      off  = (int*)alloc((size_t)(N + 1) * 4);
    int*      curs = (int*)alloc((size_t)N * 4);
    int*      csr  = (int*)alloc((size_t)E * 4);
    _Float16* Wt1  = (_Float16*)alloc(256 * 256 * 2);
    _Float16* Wt2  = (_Float16*)alloc(128 * 256 * 2);
    _Float16* Wt3  = (_Float16*)alloc(64 * 128 * 2);
    _Float16* bufC = (_Float16*)alloc((size_t)N * 256 * 2);
    _Float16* bufH = (_Float16*)alloc((size_t)N * 256 * 2);
    (void)ws_size; (void)n_in; (void)out_size;

    const int gM   = (N + 127) / 128;            // 157
    const int nCnt = (E / 2 + 255) / 256;        // 625 (2 edges/thread)
    const int nWcv = (106496 + 255) / 256;       // 416
    const int nGm1 = gM * 4;                     // 628
    const int gAgg = (N + 3) / 4;

    hipMemsetAsync(deg, 0, (size_t)N * 4, stream);
    fused_count_wconv_kernel<<<nCnt + nWcv, 256, 0, stream>>>(
        ei, deg, E, nCnt, W1, W2, W3, Wt1, Wt2, Wt3);
    scan_kernel<<<1, SCAN_THREADS, 0, stream>>>(deg, off, curs, dis, N, E);
    fused_gemm1_fill_kernel<<<nGm1 + nCnt, 256, 0, stream>>>(
        x, Wt1, bufC, N, gM, nGm1, ei, curs, csr, E);

    agg_kernel<256, true, 4, true><<<gAgg, 256, 0, stream>>>(
        bufC, dis, b1, off, csr, bufH, N, 1);
    gemm_kernel<<<dim3(gM, 2), 256, 0, stream>>>(bufH, Wt2, dis, bufC, N, 128, 256);
    agg_kernel<128, true, 4, false><<<gAgg, 256, 0, stream>>>(
        bufC, dis, b2, off, csr, bufH, N, 1);
    gemm_kernel<<<dim3(gM, 1), 256, 0, stream>>>(bufH, Wt3, dis, bufC, N, 64, 128);
    agg_kernel<64, false, 2, false><<<gAgg, 256, 0, stream>>>(
        bufC, dis, b3, off, csr, d_out, N, 0);
}